// Round 23
// baseline (2815.459 us; speedup 1.0000x reference)
//
#include <hip/hip_runtime.h>
#include <hip/hip_bf16.h>

// CLIP ViT-B/16 visual forward — Round 23: R22 (2804us) with cvt's
// nontemporal store reverted to plain int4 store (NT regressed 130->151us).
// Attention keeps the swapped-operand PV (the R22 win). All else identical.

#define LAYERS 12
#define DMODEL 768
#define NHEADS 12
#define DHEAD  64
#define FFDIM  3072
#define BATCH  32
#define SEQ    197
#define NPATCH 196
#define OUTD   512
#define MROWS  (BATCH * SEQ)   // 6304
#define MPAD   6400
#define SPAD   208
#define VSTR   208

typedef __attribute__((ext_vector_type(4))) float f32x4;
typedef __attribute__((ext_vector_type(8))) short bf16x8;

enum { M_F32 = 0, M_ACC = 1, M_GELU = 2, M_PATCH = 3, M_QKVB = 4 };

__device__ __forceinline__ float b2f(short s) {
    unsigned u = ((unsigned)(unsigned short)s) << 16;
    return __builtin_bit_cast(float, u);
}
__device__ __forceinline__ short f2b(float f) {
    __hip_bfloat16 h = __float2bfloat16(f);
    return __builtin_bit_cast(short, h);
}
__device__ __forceinline__ unsigned short f2bu(float f) {
    __hip_bfloat16 h = __float2bfloat16(f);
    return __builtin_bit_cast(unsigned short, h);
}
__device__ __forceinline__ unsigned pack2(float lo, float hi) {
    return (unsigned)f2bu(lo) | ((unsigned)f2bu(hi) << 16);
}

__device__ __forceinline__ void gl2lds16(const void* g, void* l) {
    __builtin_amdgcn_global_load_lds(
        (const __attribute__((address_space(1))) void*)g,
        (__attribute__((address_space(3))) void*)l, 16, 0, 0);
}

// ---------------------------------------------------------------- weight cvt
__global__ __launch_bounds__(256) void cvt_merged_kernel(
    const float* __restrict__ s0, __hip_bfloat16* __restrict__ d0, long n0,
    const float* __restrict__ s1, __hip_bfloat16* __restrict__ d1, long n1,
    const float* __restrict__ s2, __hip_bfloat16* __restrict__ d2, long n2,
    const float* __restrict__ s3, __hip_bfloat16* __restrict__ d3, long n3,
    const float* __restrict__ s4, __hip_bfloat16* __restrict__ d4, long n4)
{
    const long SPAN = 32768;
    long start = (long)blockIdx.x * SPAN;
    long e0 = n0, e1 = e0 + n1, e2 = e1 + n2, e3 = e2 + n3;
    const float* s; __hip_bfloat16* d; long base;
    if (start < e0)      { s = s0; d = d0; base = 0; }
    else if (start < e1) { s = s1; d = d1; base = e0; }
    else if (start < e2) { s = s2; d = d2; base = e1; }
    else if (start < e3) { s = s3; d = d3; base = e2; }
    else                 { s = s4; d = d4; base = e3; }
    long off = start - base;
    #pragma unroll 4
    for (long i = off + (long)threadIdx.x * 8; i < off + SPAN; i += 2048) {
        float4 v0 = *reinterpret_cast<const float4*>(&s[i]);
        float4 v1 = *reinterpret_cast<const float4*>(&s[i + 4]);
        int4 u;
        u.x = (int)pack2(v0.x, v0.y);
        u.y = (int)pack2(v0.z, v0.w);
        u.z = (int)pack2(v1.x, v1.y);
        u.w = (int)pack2(v1.z, v1.w);
        *reinterpret_cast<int4*>(&d[i]) = u;
    }
}

// ---------------------------------------------------------------- im2col
__global__ __launch_bounds__(256) void im2col_kernel(
    const float* __restrict__ x_inp, __hip_bfloat16* __restrict__ patches)
{
    int bp = blockIdx.x;
    int b = bp / NPATCH, p = bp % NPATCH;
    int py = p / 14, px = p % 14;
    const float* xb = x_inp + (long)b * 3 * 224 * 224;
    for (int e = threadIdx.x; e < 768; e += 256) {
        int c = e >> 8, i = (e >> 4) & 15, j = e & 15;
        patches[(long)bp * 768 + e] =
            __float2bfloat16(xb[((long)c * 224 + py * 16 + i) * 224 + px * 16 + j]);
    }
}

__global__ __launch_bounds__(256) void cls_token_kernel(
    const float* __restrict__ cls_emb, const float* __restrict__ pos_emb,
    float* __restrict__ x)
{
    int b = blockIdx.x;
    for (int d = threadIdx.x; d < DMODEL; d += 256)
        x[(long)b * SEQ * DMODEL + d] = cls_emb[d] + pos_emb[d];
}

// ---------------------------------------------------------------- layernorm
template<int OB>
__global__ __launch_bounds__(256) void ln_kernel(
    const float* __restrict__ in, void* __restrict__ out,
    const float* __restrict__ w, const float* __restrict__ bb,
    long in_stride, long out_stride, int nrows)
{
    int row = blockIdx.x * 4 + (threadIdx.x >> 6);
    if (row >= nrows) return;
    int lane = threadIdx.x & 63;
    const float* xr = in + (long)row * in_stride;

    float4 v[3];
    float s = 0.f;
    #pragma unroll
    for (int i = 0; i < 3; ++i) {
        v[i] = *reinterpret_cast<const float4*>(&xr[i * 256 + lane * 4]);
        s += v[i].x + v[i].y + v[i].z + v[i].w;
    }
    #pragma unroll
    for (int off = 32; off; off >>= 1) s += __shfl_xor(s, off);
    float mean = s * (1.0f / DMODEL);
    float sq = 0.f;
    #pragma unroll
    for (int i = 0; i < 3; ++i) {
        float a = v[i].x - mean, b2 = v[i].y - mean,
              c = v[i].z - mean, d = v[i].w - mean;
        sq += a * a + b2 * b2 + c * c + d * d;
    }
    #pragma unroll
    for (int off = 32; off; off >>= 1) sq += __shfl_xor(sq, off);
    float rstd = rsqrtf(sq * (1.0f / DMODEL) + 1e-5f);

    #pragma unroll
    for (int i = 0; i < 3; ++i) {
        int d0 = i * 256 + lane * 4;
        float4 wv = *reinterpret_cast<const float4*>(&w[d0]);
        float4 bv = *reinterpret_cast<const float4*>(&bb[d0]);
        float o0 = (v[i].x - mean) * rstd * wv.x + bv.x;
        float o1 = (v[i].y - mean) * rstd * wv.y + bv.y;
        float o2 = (v[i].z - mean) * rstd * wv.z + bv.z;
        float o3 = (v[i].w - mean) * rstd * wv.w + bv.w;
        if (OB) {
            ushort4 u;
            u.x = f2bu(o0); u.y = f2bu(o1); u.z = f2bu(o2); u.w = f2bu(o3);
            *reinterpret_cast<ushort4*>(
                &((__hip_bfloat16*)out)[(long)row * out_stride + d0]) = u;
        } else {
            float4 o = make_float4(o0, o1, o2, o3);
            *reinterpret_cast<float4*>(&((float*)out)[(long)row * out_stride + d0]) = o;
        }
    }
}

// ---------------------------------------------------------------- GEMM 64k
// 64x128 tile, BK=128, SINGLE-buffer 48KB LDS (3 blocks/CU). 4 waves, each
// 64x32 out. SWAPPED mfma operands: lane = C-row (fixed), regs = 4 cols.
template<int MODE>
__global__ __launch_bounds__(256) void gemm64k(
    const __hip_bfloat16* __restrict__ A, const __hip_bfloat16* __restrict__ W,
    const float* __restrict__ bias, float* __restrict__ Cf,
    __hip_bfloat16* __restrict__ Cb, int M, int N, int K, int NB,
    const float* __restrict__ pos)
{
    __shared__ short As[64 * 128];    // 16KB
    __shared__ short Bs[128 * 128];   // 32KB
    int tid = threadIdx.x, lane = tid & 63, wv = tid >> 6;

    int nwg = gridDim.x, bid = blockIdx.x;
    int qq = nwg >> 3, rr = nwg & 7;
    int xcd = bid & 7, idx = bid >> 3;
    int newid = (xcd < rr ? xcd * (qq + 1) : rr * (qq + 1) + (xcd - rr) * qq) + idx;

    int bm = (newid / NB) * 64, bn = (newid % NB) * 128;
    int wn = wv * 32;
    f32x4 acc[4][2] = {};

    int sr = tid >> 4, scn = tid & 15;
    int c_log = scn ^ sr;
    const short* Ag = (const short*)A + (long)(bm + sr) * K + (c_log << 3);
    const short* Bg = (const short*)W + (long)(bn + sr) * K + (c_log << 3);
    const long K16 = (long)16 * K;

    int lg = lane >> 4, lr16 = lane & 15;
    int aoff[4][4], boff[4][2];
    #pragma unroll
    for (int s = 0; s < 4; ++s) {
        int kc = (s << 2) | lg;
        #pragma unroll
        for (int i = 0; i < 4; ++i) {
            int ra = i * 16 + lr16;
            aoff[s][i] = (ra << 7) + (((kc ^ (ra & 15))) << 3);
        }
        #pragma unroll
        for (int j = 0; j < 2; ++j) {
            int rb = wn + j * 16 + lr16;
            boff[s][j] = (rb << 7) + (((kc ^ (rb & 15))) << 3);
        }
    }

    const int KT = K >> 7;
    for (int t = 0; t < KT; ++t) {
        if (t) __syncthreads();
        int kt = t << 7;
        #pragma unroll
        for (int p = 0; p < 4; ++p)
            gl2lds16(Ag + p * K16 + kt, (char*)As + p * 4096 + tid * 16);
        #pragma unroll
        for (int p = 0; p < 8; ++p)
            gl2lds16(Bg + p * K16 + kt, (char*)Bs + p * 4096 + tid * 16);
        __syncthreads();

        #pragma unroll
        for (int s = 0; s < 4; ++s) {
            bf16x8 af[4], bfr[2];
            #pragma unroll
            for (int i = 0; i < 4; ++i)
                af[i] = *reinterpret_cast<const bf16x8*>(&As[aoff[s][i]]);
            #pragma unroll
            for (int j = 0; j < 2; ++j)
                bfr[j] = *reinterpret_cast<const bf16x8*>(&Bs[boff[s][j]]);
            #pragma unroll
            for (int mi = 0; mi < 4; ++mi)
                #pragma unroll
                for (int ni = 0; ni < 2; ++ni)
                    acc[mi][ni] = __builtin_amdgcn_mfma_f32_16x16x32_bf16(
                        bfr[ni], af[mi], acc[mi][ni], 0, 0, 0);
        }
    }

    #pragma unroll
    for (int mi = 0; mi < 4; ++mi) {
        int row = bm + mi * 16 + lr16;
        if (row >= M) continue;
        #pragma unroll
        for (int ni = 0; ni < 2; ++ni) {
            int colb = bn + wn + ni * 16 + lg * 4;
            f32x4 a4 = acc[mi][ni];
            if (MODE == M_PATCH) {
                int pb = row / 196, pp = row - pb * 196;
                float* dst = &Cf[((long)(pb * SEQ + 1 + pp)) * DMODEL + colb];
                const float* pv = &pos[(long)(1 + pp) * DMODEL + colb];
                float4 pw = *reinterpret_cast<const float4*>(pv);
                float4 o = make_float4(a4[0] + pw.x, a4[1] + pw.y,
                                       a4[2] + pw.z, a4[3] + pw.w);
                *reinterpret_cast<float4*>(dst) = o;
            } else {
                float4 bw = *reinterpret_cast<const float4*>(&bias[colb]);
                float* dst = &Cf[(long)row * N + colb];
                if (MODE == M_ACC) {
                    float4 old = *reinterpret_cast<const float4*>(dst);
                    float4 o = make_float4(old.x + a4[0] + bw.x, old.y + a4[1] + bw.y,
                                           old.z + a4[2] + bw.z, old.w + a4[3] + bw.w);
                    *reinterpret_cast<float4*>(dst) = o;
                } else {
                    float4 o = make_float4(a4[0] + bw.x, a4[1] + bw.y,
                                           a4[2] + bw.z, a4[3] + bw.w);
                    *reinterpret_cast<float4*>(dst) = o;
                }
            }
        }
    }
}

// ---------------------------------------------------------------- GEMM 128sq
// 128x128 tile, BK=64, SINGLE-buffer 32KB LDS (5 blocks/CU), 4 waves (2x2).
// SWAPPED mfma operands -> packed 8B bf16 stores.
template<int MODE>
__global__ __launch_bounds__(256) void gemm128(
    const __hip_bfloat16* __restrict__ A, const __hip_bfloat16* __restrict__ W,
    const float* __restrict__ bias, __hip_bfloat16* __restrict__ Cb,
    int M, int N, int K, int NB)
{
    __shared__ short As[128 * 64];   // 16KB
    __shared__ short Bs[128 * 64];   // 16KB
    int tid = threadIdx.x, lane = tid & 63, wv = tid >> 6;

    int nwg = gridDim.x, bid = blockIdx.x;
    int qq = nwg >> 3, rr = nwg & 7;
    int xcd = bid & 7, idx = bid >> 3;
    int newid = (xcd < rr ? xcd * (qq + 1) : rr * (qq + 1) + (xcd - rr) * qq) + idx;

    int bm = (newid / NB) * 128, bn = (newid % NB) * 128;
    int wr = wv >> 1, wc = wv & 1;
    f32x4 acc[4][4] = {};

    int sr = tid >> 3, scn = tid & 7;
    int c_log = scn ^ (sr & 7);
    const short* Ag = (const short*)A + (long)(bm + sr) * K + (c_log << 3);
    const short* Bg = (const short*)W + (long)(bn + sr) * K + (c_log << 3);
    const long K32 = (long)32 * K;

    int lg = lane >> 4, lr16 = lane & 15;
    int aoff[2][4], boff[2][4];
    #pragma unroll
    for (int s = 0; s < 2; ++s) {
        int kc = (s << 2) | lg;
        #pragma unroll
        for (int i = 0; i < 4; ++i) {
            int ra = wr * 64 + i * 16 + lr16;
            aoff[s][i] = (ra << 6) + ((kc ^ (ra & 7)) << 3);
            int rb = wc * 64 + i * 16 + lr16;
            boff[s][i] = (rb << 6) + ((kc ^ (rb & 7)) << 3);
        }
    }

    const int KT = K >> 6;
    for (int t = 0; t < KT; ++t) {
        if (t) __syncthreads();
        int kt = t << 6;
        #pragma unroll
        for (int p = 0; p < 4; ++p) {
            gl2lds16(Ag + p * K32 + kt, (char*)As + p * 4096 + tid * 16);
            gl2lds16(Bg + p * K32 + kt, (char*)Bs + p * 4096 + tid * 16);
        }
        __syncthreads();

        #pragma unroll
        for (int s = 0; s < 2; ++s) {
            bf16x8 af[4], bfr[4];
            #pragma unroll
            for (int i = 0; i < 4; ++i)
                af[i] = *reinterpret_cast<const bf16x8*>(&As[aoff[s][i]]);
            #pragma unroll
            for (int j = 0; j < 4; ++j)
                bfr[j] = *reinterpret_cast<const bf16x8*>(&Bs[boff[s][j]]);
            #pragma unroll
            for (int mi = 0; mi < 4; ++mi)
                #pragma unroll
                for (int ni = 0; ni < 4; ++ni)
                    acc[mi][ni] = __builtin_amdgcn_mfma_f32_16x16x32_bf16(
                        bfr[ni], af[mi], acc[mi][ni], 0, 0, 0);
        }
    }

    #pragma unroll
    for (int mi = 0; mi < 4; ++mi) {
        int row = bm + wr * 64 + mi * 16 + lr16;
        if (row >= M) continue;
        #pragma unroll
        for (int ni = 0; ni < 4; ++ni) {
            int colb = bn + wc * 64 + ni * 16 + lg * 4;
            f32x4 a4 = acc[mi][ni];
            float4 bw = *reinterpret_cast<const float4*>(&bias[colb]);
            float v0 = a4[0] + bw.x, v1 = a4[1] + bw.y;
            float v2 = a4[2] + bw.z, v3 = a4[3] + bw.w;
            if (MODE == M_GELU) {
                v0 = v0 / (1.f + __expf(-1.702f * v0));
                v1 = v1 / (1.f + __expf(-1.702f * v1));
                v2 = v2 / (1.f + __expf(-1.702f * v2));
                v3 = v3 / (1.f + __expf(-1.702f * v3));
            }
            uint2 u;
            u.x = pack2(v0, v1);
            u.y = pack2(v2, v3);
            *reinterpret_cast<uint2*>(&Cb[(long)row * N + colb]) = u;
        }
    }
}

// ---------------------------------------------------------------- attention
// one block (256 thr, 4 waves) per (b,h); K,V staged in LDS. PV uses
// SWAPPED operands: lane holds q-row, regs = 4 consecutive d-cols -> 8B stores.
__global__ __launch_bounds__(256) void attn_kernel(
    const __hip_bfloat16* __restrict__ qkv, __hip_bfloat16* __restrict__ o)
{
    int bh = blockIdx.x;
    int b = bh / NHEADS, h = bh % NHEADS;
    int tid = threadIdx.x, lane = tid & 63, wv = tid >> 6;
    __shared__ short Ks[SPAD * 64];
    __shared__ short Vt[64 * VSTR];
    __shared__ short Ps[4][16 * VSTR];
    const short* base = (const short*)qkv + (long)b * SEQ * 2304;

    for (int idx = tid; idx < SPAD * 8; idx += 256) {
        int r = idx >> 3, c = idx & 7;
        int4 val = make_int4(0, 0, 0, 0);
        if (r < SEQ)
            val = *reinterpret_cast<const int4*>(base + (long)r * 2304 + 768 + h * 64 + c * 8);
        *reinterpret_cast<int4*>(&Ks[r * 64 + ((c ^ (r & 7)) << 3)]) = val;
    }
    for (int idx = tid; idx < SPAD * 64; idx += 256) {
        int k = idx >> 6, d = idx & 63;
        short v = (k < SEQ) ? base[(long)k * 2304 + 1536 + h * 64 + d] : (short)0;
        Vt[d * VSTR + k] = v;
    }
    __syncthreads();

    int lg = lane >> 4, lr = lane & 15;
    short* Pw = Ps[wv];

    for (int ch = wv; ch < 13; ch += 4) {
        int q0 = ch * 16;
        const short* qp = (const short*)qkv +
            ((long)(b * SEQ) + q0 + lr) * 2304 + h * 64 + (lg << 3);
        bf16x8 qa = *reinterpret_cast<const bf16x8*>(qp);
        bf16x8 qb = *reinterpret_cast<const bf16x8*>(qp + 32);

        f32x4 sc[13];
        #pragma unroll
        for (int f = 0; f < 13; ++f) sc[f] = (f32x4){0.f, 0.f, 0.f, 0.f};
        #pragma unroll
        for (int f = 0; f < 13; ++f) {
            int row = f * 16 + lr;
            int sw = row & 7;
            const short* kr = &Ks[row * 64];
            bf16x8 k0 = *reinterpret_cast<const bf16x8*>(&kr[((lg + 0) ^ sw) << 3]);
            bf16x8 k1 = *reinterpret_cast<const bf16x8*>(&kr[((lg + 4) ^ sw) << 3]);
            sc[f] = __builtin_amdgcn_mfma_f32_16x16x32_bf16(qa, k0, sc[f], 0, 0, 0);
            sc[f] = __builtin_amdgcn_mfma_f32_16x16x32_bf16(qb, k1, sc[f], 0, 0, 0);
        }

        float mrow[4] = {-1e30f, -1e30f, -1e30f, -1e30f};
        #pragma unroll
        for (int f = 0; f < 13; ++f) {
            bool ok = f * 16 + lr < SEQ;
            #pragma unroll
            for (int r = 0; r < 4; ++r)
                if (ok) mrow[r] = fmaxf(mrow[r], sc[f][r] * 0.125f);
        }
        #pragma unroll
        for (int r = 0; r < 4; ++r)
            #pragma unroll
            for (int off = 8; off; off >>= 1)
                mrow[r] = fmaxf(mrow[r], __shfl_xor(mrow[r], off));
        float esum[4] = {0.f, 0.f, 0.f, 0.f};
        #pragma unroll
        for (int f = 0; f < 13; ++f) {
            bool ok = f * 16 + lr < SEQ;
            #pragma unroll
            for (int r = 0; r < 4; ++r) {
                float e = ok ? __expf(sc[f][r] * 0.125f - mrow[r]) : 0.f;
                sc[f][r] = e;
                esum[r] += e;
            }
        }
        #pragma unroll
        for (int r = 0; r < 4; ++r)
            #pragma unroll
            for (int off = 8; off; off >>= 1)
                esum[r] += __shfl_xor(esum[r], off);
        float inv[4];
        #pragma unroll
        for (int r = 0; r < 4; ++r) inv[r] = 1.0f / esum[r];

        #pragma unroll
        for (int f = 0; f < 13; ++f)
            #pragma unroll
            for (int r = 0; r < 4; ++r)
                Pw[(lg * 4 + r) * VSTR + f * 16 + lr] = f2b(sc[f][r] * inv[r]);

        f32x4 oa[4] = {};
        #pragma unroll
        for (int ks = 0; ks < 7; ++ks) {
            int kb = ks * 32 + (lg << 3);
            bf16x8 pa = {};
            if (kb < SPAD) pa = *reinterpret_cast<const bf16x8*>(&Pw[lr * VSTR + kb]);
            #pragma unroll
            for (int d = 0; d < 4; ++d) {
                bf16x8 vb = {};
                if (kb < SPAD)
                    vb = *reinterpret_cast<const bf16x8*>(&Vt[(d * 16 + lr) * VSTR + kb]);
                oa[d] = __builtin_amdgcn_mfma_f32_16x16x32_bf16(vb, pa, oa[d], 0, 0, 0);
            }
        }

        int q = q0 + lr;
        if (q < SEQ) {
            __hip_bfloat16* orow = &o[((long)(b * SEQ + q)) * DMODEL + h * 64];
            #pragma unroll
            for (int d = 0; d < 4; ++d) {
                uint2 u;
                u.x = pack2(oa[d][0], oa[d][1]);
                u.y = pack2(oa[d][2], oa[d][3]);
                *reinterpret_cast<uint2*>(&orow[d * 16 + lg * 4]) = u;
            }
        }
    }
}

// ---------------------------------------------------------------- final proj
__global__ __launch_bounds__(256) void proj_kernel(
    const float* __restrict__ cls_ln, const float* __restrict__ proj,
    float* __restrict__ out)
{
    int idx = blockIdx.x * 256 + threadIdx.x;
    int m = idx >> 9, n = idx & 511;
    float s = 0.f;
    #pragma unroll 8
    for (int k = 0; k < 768; ++k)
        s += cls_ln[m * 768 + k] * proj[k * 512 + n];
    out[idx] = s;
}

// ---------------------------------------------------------------- launcher
extern "C" void kernel_launch(void* const* d_in, const int* in_sizes, int n_in,
                              void* d_out, int out_size, void* d_ws, size_t ws_size,
                              hipStream_t stream) {
    const float* x_inp    = (const float*)d_in[0];
    const float* conv_w   = (const float*)d_in[1];
    const float* cls_emb  = (const float*)d_in[2];
    const float* pos_emb  = (const float*)d_in[3];
    const float* ln_pre_w = (const float*)d_in[4];
    const float* ln_pre_b = (const float*)d_in[5];
    const float* ln1_w    = (const float*)d_in[6];
    const float* ln1_b    = (const float*)d_in[7];
    const float* qkv_w    = (const float*)d_in[8];
    const float* qkv_b    = (const float*)d_in[9];
    const float* out_w    = (const float*)d_in[10];
    const float* out_b    = (const float*)d_in[11];
    const float* ln2_w    = (const float*)d_in[12];
    const float* ln2_b    = (const float*)d_in[13];
    const float* fc1_w    = (const float*)d_in[14];
    const float* fc1_b    = (const float*)d_in[15];
    const float* fc2_w    = (const float*)d_in[16];
    const float* fc2_b    = (const float*)d_in[17];
    const float* ln_post_w= (const float*)d_in[18];
    const float* ln_post_b= (const float*)d_in[19];
    const float* proj     = (const float*)d_in[20];

    char* w = (char*)d_ws;
    __hip_bfloat16* wqkv = (__hip_bfloat16*)w; w += (size_t)LAYERS * 2304 * DMODEL * 2;
    __hip_bfloat16* wout = (__hip_bfloat16*)w; w += (size_t)LAYERS * DMODEL * DMODEL * 2;
    __hip_bfloat16* wfc1 = (__hip_bfloat16*)w; w += (size_t)LAYERS * FFDIM * DMODEL * 2;
    __hip_bfloat16* wfc2 = (__hip_bfloat16*)w; w += (size_t)LAYERS * DMODEL * FFDIM * 2;
    __hip_bfloat16* wconv= (__hip_bfloat16*)w; w += (size_t)DMODEL * DMODEL * 2;
    float* x             = (float*)w;          w += (size_t)MROWS * DMODEL * 4;
    __hip_bfloat16* y    = (__hip_bfloat16*)w; w += (size_t)MPAD * DMODEL * 2;
    __hip_bfloat16* qkvb = (__hip_bfloat16*)w; w += (size_t)MPAD * 2304 * 2;
    __hip_bfloat16* attno= (__hip_bfloat16*)w; w += (size_t)MPAD * DMODEL * 2;
    __hip_bfloat16* h1   = (__hip_bfloat16*)w; w += (size_t)MPAD * FFDIM * 2;
    __hip_bfloat16* patches = (__hip_bfloat16*)w; w += (size_t)NPATCH * BATCH * DMODEL * 2;
    float* clsb          = (float*)w;          w += (size_t)BATCH * DMODEL * 4;

    const long nqkv = (long)LAYERS * 2304 * DMODEL;
    const long nout = (long)LAYERS * DMODEL * DMODEL;
    const long nfc  = (long)LAYERS * FFDIM * DMODEL;
    const long ncv  = (long)DMODEL * DMODEL;
    int nblk = (int)((nqkv + nout + 2 * nfc + ncv) / 32768);
    cvt_merged_kernel<<<nblk, 256, 0, stream>>>(
        qkv_w, wqkv, nqkv, out_w, wout, nout,
        fc1_w, wfc1, nfc, fc2_w, wfc2, nfc, conv_w, wconv, ncv);

    im2col_kernel<<<NPATCH * BATCH, 256, 0, stream>>>(x_inp, patches);
    gemm64k<M_PATCH><<<98 * 6, 256, 0, stream>>>(
        patches, wconv, nullptr, x, nullptr, NPATCH * BATCH, DMODEL, DMODEL, 6, pos_emb);
    cls_token_kernel<<<BATCH, 256, 0, stream>>>(cls_emb, pos_emb, x);
    ln_kernel<0><<<MROWS / 4, 256, 0, stream>>>(x, x, ln_pre_w, ln_pre_b,
                                                DMODEL, DMODEL, MROWS);

    for (int l = 0; l < LAYERS; ++l) {
        ln_kernel<1><<<MROWS / 4, 256, 0, stream>>>(x, y, ln1_w + l * DMODEL,
                                                    ln1_b + l * DMODEL, DMODEL, DMODEL, MROWS);
        gemm128<M_QKVB><<<50 * 18, 256, 0, stream>>>(
            y, wqkv + (long)l * 2304 * DMODEL, qkv_b + (long)l * 2304, qkvb,
            MROWS, 2304, DMODEL, 18);
        attn_kernel<<<BATCH * NHEADS, 256, 0, stream>>>(qkvb, attno);
        gemm64k<M_ACC><<<99 * 6, 256, 0, stream>>>(
            attno, wout + (long)l * DMODEL * DMODEL, out_b + (long)l * DMODEL, x, nullptr,
            MROWS, DMODEL, DMODEL, 6, nullptr);
        ln_kernel<1><<<MROWS / 4, 256, 0, stream>>>(x, y, ln2_w + l * DMODEL,
                                                    ln2_b + l * DMODEL, DMODEL, DMODEL, MROWS);
        gemm128<M_GELU><<<50 * 24, 256, 0, stream>>>(
            y, wfc1 + (long)l * FFDIM * DMODEL, fc1_b + (long)l * FFDIM, h1,
            MROWS, FFDIM, DMODEL, 24);
        gemm64k<M_ACC><<<99 * 6, 256, 0, stream>>>(
            h1, wfc2 + (long)l * DMODEL * FFDIM, fc2_b + (long)l * DMODEL, x, nullptr,
            MROWS, DMODEL, FFDIM, 6, nullptr);
    }

    ln_kernel<0><<<8, 256, 0, stream>>>(x, clsb, ln_post_w, ln_post_b,
                                        (long)SEQ * DMODEL, DMODEL, BATCH);
    proj_kernel<<<(BATCH * OUTD) / 256, 256, 0, stream>>>(clsb, proj, (float*)d_out);
}

// Round 24
// 2769.403 us; speedup vs baseline: 1.0166x; 1.0166x over previous
//
#include <hip/hip_runtime.h>
#include <hip/hip_bf16.h>

// CLIP ViT-B/16 visual forward — Round 24: R23 with NONTEMPORAL LOADS in cvt
// (the 342MB f32 source is single-use; keep it out of L2/L3 so the bf16
// weights the GEMMs re-read stay cached). Stores stay cached (NT stores
// regressed in R22). Everything else identical to R22/R23 best (~2804us).

#define LAYERS 12
#define DMODEL 768
#define NHEADS 12
#define DHEAD  64
#define FFDIM  3072
#define BATCH  32
#define SEQ    197
#define NPATCH 196
#define OUTD   512
#define MROWS  (BATCH * SEQ)   // 6304
#define MPAD   6400
#define SPAD   208
#define VSTR   208

typedef __attribute__((ext_vector_type(4))) float f32x4;
typedef __attribute__((ext_vector_type(8))) short bf16x8;

enum { M_F32 = 0, M_ACC = 1, M_GELU = 2, M_PATCH = 3, M_QKVB = 4 };

__device__ __forceinline__ float b2f(short s) {
    unsigned u = ((unsigned)(unsigned short)s) << 16;
    return __builtin_bit_cast(float, u);
}
__device__ __forceinline__ short f2b(float f) {
    __hip_bfloat16 h = __float2bfloat16(f);
    return __builtin_bit_cast(short, h);
}
__device__ __forceinline__ unsigned short f2bu(float f) {
    __hip_bfloat16 h = __float2bfloat16(f);
    return __builtin_bit_cast(unsigned short, h);
}
__device__ __forceinline__ unsigned pack2(float lo, float hi) {
    return (unsigned)f2bu(lo) | ((unsigned)f2bu(hi) << 16);
}

__device__ __forceinline__ void gl2lds16(const void* g, void* l) {
    __builtin_amdgcn_global_load_lds(
        (const __attribute__((address_space(1))) void*)g,
        (__attribute__((address_space(3))) void*)l, 16, 0, 0);
}

// ---------------------------------------------------------------- weight cvt
__global__ __launch_bounds__(256) void cvt_merged_kernel(
    const float* __restrict__ s0, __hip_bfloat16* __restrict__ d0, long n0,
    const float* __restrict__ s1, __hip_bfloat16* __restrict__ d1, long n1,
    const float* __restrict__ s2, __hip_bfloat16* __restrict__ d2, long n2,
    const float* __restrict__ s3, __hip_bfloat16* __restrict__ d3, long n3,
    const float* __restrict__ s4, __hip_bfloat16* __restrict__ d4, long n4)
{
    const long SPAN = 32768;
    long start = (long)blockIdx.x * SPAN;
    long e0 = n0, e1 = e0 + n1, e2 = e1 + n2, e3 = e2 + n3;
    const float* s; __hip_bfloat16* d; long base;
    if (start < e0)      { s = s0; d = d0; base = 0; }
    else if (start < e1) { s = s1; d = d1; base = e0; }
    else if (start < e2) { s = s2; d = d2; base = e1; }
    else if (start < e3) { s = s3; d = d3; base = e2; }
    else                 { s = s4; d = d4; base = e3; }
    long off = start - base;
    #pragma unroll 4
    for (long i = off + (long)threadIdx.x * 8; i < off + SPAN; i += 2048) {
        f32x4 v0 = __builtin_nontemporal_load(reinterpret_cast<const f32x4*>(&s[i]));
        f32x4 v1 = __builtin_nontemporal_load(reinterpret_cast<const f32x4*>(&s[i + 4]));
        int4 u;
        u.x = (int)pack2(v0[0], v0[1]);
        u.y = (int)pack2(v0[2], v0[3]);
        u.z = (int)pack2(v1[0], v1[1]);
        u.w = (int)pack2(v1[2], v1[3]);
        *reinterpret_cast<int4*>(&d[i]) = u;
    }
}

// ---------------------------------------------------------------- im2col
__global__ __launch_bounds__(256) void im2col_kernel(
    const float* __restrict__ x_inp, __hip_bfloat16* __restrict__ patches)
{
    int bp = blockIdx.x;
    int b = bp / NPATCH, p = bp % NPATCH;
    int py = p / 14, px = p % 14;
    const float* xb = x_inp + (long)b * 3 * 224 * 224;
    for (int e = threadIdx.x; e < 768; e += 256) {
        int c = e >> 8, i = (e >> 4) & 15, j = e & 15;
        patches[(long)bp * 768 + e] =
            __float2bfloat16(xb[((long)c * 224 + py * 16 + i) * 224 + px * 16 + j]);
    }
}

__global__ __launch_bounds__(256) void cls_token_kernel(
    const float* __restrict__ cls_emb, const float* __restrict__ pos_emb,
    float* __restrict__ x)
{
    int b = blockIdx.x;
    for (int d = threadIdx.x; d < DMODEL; d += 256)
        x[(long)b * SEQ * DMODEL + d] = cls_emb[d] + pos_emb[d];
}

// ---------------------------------------------------------------- layernorm
template<int OB>
__global__ __launch_bounds__(256) void ln_kernel(
    const float* __restrict__ in, void* __restrict__ out,
    const float* __restrict__ w, const float* __restrict__ bb,
    long in_stride, long out_stride, int nrows)
{
    int row = blockIdx.x * 4 + (threadIdx.x >> 6);
    if (row >= nrows) return;
    int lane = threadIdx.x & 63;
    const float* xr = in + (long)row * in_stride;

    float4 v[3];
    float s = 0.f;
    #pragma unroll
    for (int i = 0; i < 3; ++i) {
        v[i] = *reinterpret_cast<const float4*>(&xr[i * 256 + lane * 4]);
        s += v[i].x + v[i].y + v[i].z + v[i].w;
    }
    #pragma unroll
    for (int off = 32; off; off >>= 1) s += __shfl_xor(s, off);
    float mean = s * (1.0f / DMODEL);
    float sq = 0.f;
    #pragma unroll
    for (int i = 0; i < 3; ++i) {
        float a = v[i].x - mean, b2 = v[i].y - mean,
              c = v[i].z - mean, d = v[i].w - mean;
        sq += a * a + b2 * b2 + c * c + d * d;
    }
    #pragma unroll
    for (int off = 32; off; off >>= 1) sq += __shfl_xor(sq, off);
    float rstd = rsqrtf(sq * (1.0f / DMODEL) + 1e-5f);

    #pragma unroll
    for (int i = 0; i < 3; ++i) {
        int d0 = i * 256 + lane * 4;
        float4 wv = *reinterpret_cast<const float4*>(&w[d0]);
        float4 bv = *reinterpret_cast<const float4*>(&bb[d0]);
        float o0 = (v[i].x - mean) * rstd * wv.x + bv.x;
        float o1 = (v[i].y - mean) * rstd * wv.y + bv.y;
        float o2 = (v[i].z - mean) * rstd * wv.z + bv.z;
        float o3 = (v[i].w - mean) * rstd * wv.w + bv.w;
        if (OB) {
            ushort4 u;
            u.x = f2bu(o0); u.y = f2bu(o1); u.z = f2bu(o2); u.w = f2bu(o3);
            *reinterpret_cast<ushort4*>(
                &((__hip_bfloat16*)out)[(long)row * out_stride + d0]) = u;
        } else {
            float4 o = make_float4(o0, o1, o2, o3);
            *reinterpret_cast<float4*>(&((float*)out)[(long)row * out_stride + d0]) = o;
        }
    }
}

// ---------------------------------------------------------------- GEMM 64k
// 64x128 tile, BK=128, SINGLE-buffer 48KB LDS (3 blocks/CU). 4 waves, each
// 64x32 out. SWAPPED mfma operands: lane = C-row (fixed), regs = 4 cols.
template<int MODE>
__global__ __launch_bounds__(256) void gemm64k(
    const __hip_bfloat16* __restrict__ A, const __hip_bfloat16* __restrict__ W,
    const float* __restrict__ bias, float* __restrict__ Cf,
    __hip_bfloat16* __restrict__ Cb, int M, int N, int K, int NB,
    const float* __restrict__ pos)
{
    __shared__ short As[64 * 128];    // 16KB
    __shared__ short Bs[128 * 128];   // 32KB
    int tid = threadIdx.x, lane = tid & 63, wv = tid >> 6;

    int nwg = gridDim.x, bid = blockIdx.x;
    int qq = nwg >> 3, rr = nwg & 7;
    int xcd = bid & 7, idx = bid >> 3;
    int newid = (xcd < rr ? xcd * (qq + 1) : rr * (qq + 1) + (xcd - rr) * qq) + idx;

    int bm = (newid / NB) * 64, bn = (newid % NB) * 128;
    int wn = wv * 32;
    f32x4 acc[4][2] = {};

    int sr = tid >> 4, scn = tid & 15;
    int c_log = scn ^ sr;
    const short* Ag = (const short*)A + (long)(bm + sr) * K + (c_log << 3);
    const short* Bg = (const short*)W + (long)(bn + sr) * K + (c_log << 3);
    const long K16 = (long)16 * K;

    int lg = lane >> 4, lr16 = lane & 15;
    int aoff[4][4], boff[4][2];
    #pragma unroll
    for (int s = 0; s < 4; ++s) {
        int kc = (s << 2) | lg;
        #pragma unroll
        for (int i = 0; i < 4; ++i) {
            int ra = i * 16 + lr16;
            aoff[s][i] = (ra << 7) + (((kc ^ (ra & 15))) << 3);
        }
        #pragma unroll
        for (int j = 0; j < 2; ++j) {
            int rb = wn + j * 16 + lr16;
            boff[s][j] = (rb << 7) + (((kc ^ (rb & 15))) << 3);
        }
    }

    const int KT = K >> 7;
    for (int t = 0; t < KT; ++t) {
        if (t) __syncthreads();
        int kt = t << 7;
        #pragma unroll
        for (int p = 0; p < 4; ++p)
            gl2lds16(Ag + p * K16 + kt, (char*)As + p * 4096 + tid * 16);
        #pragma unroll
        for (int p = 0; p < 8; ++p)
            gl2lds16(Bg + p * K16 + kt, (char*)Bs + p * 4096 + tid * 16);
        __syncthreads();

        #pragma unroll
        for (int s = 0; s < 4; ++s) {
            bf16x8 af[4], bfr[2];
            #pragma unroll
            for (int i = 0; i < 4; ++i)
                af[i] = *reinterpret_cast<const bf16x8*>(&As[aoff[s][i]]);
            #pragma unroll
            for (int j = 0; j < 2; ++j)
                bfr[j] = *reinterpret_cast<const bf16x8*>(&Bs[boff[s][j]]);
            #pragma unroll
            for (int mi = 0; mi < 4; ++mi)
                #pragma unroll
                for (int ni = 0; ni < 2; ++ni)
                    acc[mi][ni] = __builtin_amdgcn_mfma_f32_16x16x32_bf16(
                        bfr[ni], af[mi], acc[mi][ni], 0, 0, 0);
        }
    }

    #pragma unroll
    for (int mi = 0; mi < 4; ++mi) {
        int row = bm + mi * 16 + lr16;
        if (row >= M) continue;
        #pragma unroll
        for (int ni = 0; ni < 2; ++ni) {
            int colb = bn + wn + ni * 16 + lg * 4;
            f32x4 a4 = acc[mi][ni];
            if (MODE == M_PATCH) {
                int pb = row / 196, pp = row - pb * 196;
                float* dst = &Cf[((long)(pb * SEQ + 1 + pp)) * DMODEL + colb];
                const float* pv = &pos[(long)(1 + pp) * DMODEL + colb];
                float4 pw = *reinterpret_cast<const float4*>(pv);
                float4 o = make_float4(a4[0] + pw.x, a4[1] + pw.y,
                                       a4[2] + pw.z, a4[3] + pw.w);
                *reinterpret_cast<float4*>(dst) = o;
            } else {
                float4 bw = *reinterpret_cast<const float4*>(&bias[colb]);
                float* dst = &Cf[(long)row * N + colb];
                if (MODE == M_ACC) {
                    float4 old = *reinterpret_cast<const float4*>(dst);
                    float4 o = make_float4(old.x + a4[0] + bw.x, old.y + a4[1] + bw.y,
                                           old.z + a4[2] + bw.z, old.w + a4[3] + bw.w);
                    *reinterpret_cast<float4*>(dst) = o;
                } else {
                    float4 o = make_float4(a4[0] + bw.x, a4[1] + bw.y,
                                           a4[2] + bw.z, a4[3] + bw.w);
                    *reinterpret_cast<float4*>(dst) = o;
                }
            }
        }
    }
}

// ---------------------------------------------------------------- GEMM 128sq
// 128x128 tile, BK=64, SINGLE-buffer 32KB LDS (5 blocks/CU), 4 waves (2x2).
// SWAPPED mfma operands -> packed 8B bf16 stores.
template<int MODE>
__global__ __launch_bounds__(256) void gemm128(
    const __hip_bfloat16* __restrict__ A, const __hip_bfloat16* __restrict__ W,
    const float* __restrict__ bias, __hip_bfloat16* __restrict__ Cb,
    int M, int N, int K, int NB)
{
    __shared__ short As[128 * 64];   // 16KB
    __shared__ short Bs[128 * 64];   // 16KB
    int tid = threadIdx.x, lane = tid & 63, wv = tid >> 6;

    int nwg = gridDim.x, bid = blockIdx.x;
    int qq = nwg >> 3, rr = nwg & 7;
    int xcd = bid & 7, idx = bid >> 3;
    int newid = (xcd < rr ? xcd * (qq + 1) : rr * (qq + 1) + (xcd - rr) * qq) + idx;

    int bm = (newid / NB) * 128, bn = (newid % NB) * 128;
    int wr = wv >> 1, wc = wv & 1;
    f32x4 acc[4][4] = {};

    int sr = tid >> 3, scn = tid & 7;
    int c_log = scn ^ (sr & 7);
    const short* Ag = (const short*)A + (long)(bm + sr) * K + (c_log << 3);
    const short* Bg = (const short*)W + (long)(bn + sr) * K + (c_log << 3);
    const long K32 = (long)32 * K;

    int lg = lane >> 4, lr16 = lane & 15;
    int aoff[2][4], boff[2][4];
    #pragma unroll
    for (int s = 0; s < 2; ++s) {
        int kc = (s << 2) | lg;
        #pragma unroll
        for (int i = 0; i < 4; ++i) {
            int ra = wr * 64 + i * 16 + lr16;
            aoff[s][i] = (ra << 6) + ((kc ^ (ra & 7)) << 3);
            int rb = wc * 64 + i * 16 + lr16;
            boff[s][i] = (rb << 6) + ((kc ^ (rb & 7)) << 3);
        }
    }

    const int KT = K >> 6;
    for (int t = 0; t < KT; ++t) {
        if (t) __syncthreads();
        int kt = t << 6;
        #pragma unroll
        for (int p = 0; p < 4; ++p) {
            gl2lds16(Ag + p * K32 + kt, (char*)As + p * 4096 + tid * 16);
            gl2lds16(Bg + p * K32 + kt, (char*)Bs + p * 4096 + tid * 16);
        }
        __syncthreads();

        #pragma unroll
        for (int s = 0; s < 2; ++s) {
            bf16x8 af[4], bfr[4];
            #pragma unroll
            for (int i = 0; i < 4; ++i)
                af[i] = *reinterpret_cast<const bf16x8*>(&As[aoff[s][i]]);
            #pragma unroll
            for (int j = 0; j < 4; ++j)
                bfr[j] = *reinterpret_cast<const bf16x8*>(&Bs[boff[s][j]]);
            #pragma unroll
            for (int mi = 0; mi < 4; ++mi)
                #pragma unroll
                for (int ni = 0; ni < 4; ++ni)
                    acc[mi][ni] = __builtin_amdgcn_mfma_f32_16x16x32_bf16(
                        bfr[ni], af[mi], acc[mi][ni], 0, 0, 0);
        }
    }

    #pragma unroll
    for (int mi = 0; mi < 4; ++mi) {
        int row = bm + wr * 64 + mi * 16 + lr16;
        if (row >= M) continue;
        #pragma unroll
        for (int ni = 0; ni < 4; ++ni) {
            int colb = bn + wc * 64 + ni * 16 + lg * 4;
            f32x4 a4 = acc[mi][ni];
            float4 bw = *reinterpret_cast<const float4*>(&bias[colb]);
            float v0 = a4[0] + bw.x, v1 = a4[1] + bw.y;
            float v2 = a4[2] + bw.z, v3 = a4[3] + bw.w;
            if (MODE == M_GELU) {
                v0 = v0 / (1.f + __expf(-1.702f * v0));
                v1 = v1 / (1.f + __expf(-1.702f * v1));
                v2 = v2 / (1.f + __expf(-1.702f * v2));
                v3 = v3 / (1.f + __expf(-1.702f * v3));
            }
            uint2 u;
            u.x = pack2(v0, v1);
            u.y = pack2(v2, v3);
            *reinterpret_cast<uint2*>(&Cb[(long)row * N + colb]) = u;
        }
    }
}

// ---------------------------------------------------------------- attention
// one block (256 thr, 4 waves) per (b,h); K,V staged in LDS. PV uses
// SWAPPED operands: lane holds q-row, regs = 4 consecutive d-cols -> 8B stores.
__global__ __launch_bounds__(256) void attn_kernel(
    const __hip_bfloat16* __restrict__ qkv, __hip_bfloat16* __restrict__ o)
{
    int bh = blockIdx.x;
    int b = bh / NHEADS, h = bh % NHEADS;
    int tid = threadIdx.x, lane = tid & 63, wv = tid >> 6;
    __shared__ short Ks[SPAD * 64];
    __shared__ short Vt[64 * VSTR];
    __shared__ short Ps[4][16 * VSTR];
    const short* base = (const short*)qkv + (long)b * SEQ * 2304;

    for (int idx = tid; idx < SPAD * 8; idx += 256) {
        int r = idx >> 3, c = idx & 7;
        int4 val = make_int4(0, 0, 0, 0);
        if (r < SEQ)
            val = *reinterpret_cast<const int4*>(base + (long)r * 2304 + 768 + h * 64 + c * 8);
        *reinterpret_cast<int4*>(&Ks[r * 64 + ((c ^ (r & 7)) << 3)]) = val;
    }
    for (int idx = tid; idx < SPAD * 64; idx += 256) {
        int k = idx >> 6, d = idx & 63;
        short v = (k < SEQ) ? base[(long)k * 2304 + 1536 + h * 64 + d] : (short)0;
        Vt[d * VSTR + k] = v;
    }
    __syncthreads();

    int lg = lane >> 4, lr = lane & 15;
    short* Pw = Ps[wv];

    for (int ch = wv; ch < 13; ch += 4) {
        int q0 = ch * 16;
        const short* qp = (const short*)qkv +
            ((long)(b * SEQ) + q0 + lr) * 2304 + h * 64 + (lg << 3);
        bf16x8 qa = *reinterpret_cast<const bf16x8*>(qp);
        bf16x8 qb = *reinterpret_cast<const bf16x8*>(qp + 32);

        f32x4 sc[13];
        #pragma unroll
        for (int f = 0; f < 13; ++f) sc[f] = (f32x4){0.f, 0.f, 0.f, 0.f};
        #pragma unroll
        for (int f = 0; f < 13; ++f) {
            int row = f * 16 + lr;
            int sw = row & 7;
            const short* kr = &Ks[row * 64];
            bf16x8 k0 = *reinterpret_cast<const bf16x8*>(&kr[((lg + 0) ^ sw) << 3]);
            bf16x8 k1 = *reinterpret_cast<const bf16x8*>(&kr[((lg + 4) ^ sw) << 3]);
            sc[f] = __builtin_amdgcn_mfma_f32_16x16x32_bf16(qa, k0, sc[f], 0, 0, 0);
            sc[f] = __builtin_amdgcn_mfma_f32_16x16x32_bf16(qb, k1, sc[f], 0, 0, 0);
        }

        float mrow[4] = {-1e30f, -1e30f, -1e30f, -1e30f};
        #pragma unroll
        for (int f = 0; f < 13; ++f) {
            bool ok = f * 16 + lr < SEQ;
            #pragma unroll
            for (int r = 0; r < 4; ++r)
                if (ok) mrow[r] = fmaxf(mrow[r], sc[f][r] * 0.125f);
        }
        #pragma unroll
        for (int r = 0; r < 4; ++r)
            #pragma unroll
            for (int off = 8; off; off >>= 1)
                mrow[r] = fmaxf(mrow[r], __shfl_xor(mrow[r], off));
        float esum[4] = {0.f, 0.f, 0.f, 0.f};
        #pragma unroll
        for (int f = 0; f < 13; ++f) {
            bool ok = f * 16 + lr < SEQ;
            #pragma unroll
            for (int r = 0; r < 4; ++r) {
                float e = ok ? __expf(sc[f][r] * 0.125f - mrow[r]) : 0.f;
                sc[f][r] = e;
                esum[r] += e;
            }
        }
        #pragma unroll
        for (int r = 0; r < 4; ++r)
            #pragma unroll
            for (int off = 8; off; off >>= 1)
                esum[r] += __shfl_xor(esum[r], off);
        float inv[4];
        #pragma unroll
        for (int r = 0; r < 4; ++r) inv[r] = 1.0f / esum[r];

        #pragma unroll
        for (int f = 0; f < 13; ++f)
            #pragma unroll
            for (int r = 0; r < 4; ++r)
                Pw[(lg * 4 + r) * VSTR + f * 16 + lr] = f2b(sc[f][r] * inv[r]);

        f32x4 oa[4] = {};
        #pragma unroll
        for (int ks = 0; ks < 7; ++ks) {
            int kb = ks * 32 + (lg << 3);
            bf16x8 pa = {};
            if (kb < SPAD) pa = *reinterpret_cast<const bf16x8*>(&Pw[lr * VSTR + kb]);
            #pragma unroll
            for (int d = 0; d < 4; ++d) {
                bf16x8 vb = {};
                if (kb < SPAD)
                    vb = *reinterpret_cast<const bf16x8*>(&Vt[(d * 16 + lr) * VSTR + kb]);
                oa[d] = __builtin_amdgcn_mfma_f32_16x16x32_bf16(vb, pa, oa[d], 0, 0, 0);
            }
        }

        int q = q0 + lr;
        if (q < SEQ) {
            __hip_bfloat16* orow = &o[((long)(b * SEQ + q)) * DMODEL + h * 64];
            #pragma unroll
            for (int d = 0; d < 4; ++d) {
                uint2 u;
                u.x = pack2(oa[d][0], oa[d][1]);
                u.y = pack2(oa[d][2], oa[d][3]);
                *reinterpret_cast<uint2*>(&orow[d * 16 + lg * 4]) = u;
            }
        }
    }
}

// ---------------------------------------------------------------- final proj
__global__ __launch_bounds__(256) void proj_kernel(
    const float* __restrict__ cls_ln, const float* __restrict__ proj,
    float* __restrict__ out)
{
    int idx = blockIdx.x * 256 + threadIdx.x;
    int m = idx >> 9, n = idx & 511;
    float s = 0.f;
    #pragma unroll 8
    for (int k = 0; k < 768; ++k)
        s += cls_ln[m * 768 + k] * proj[k * 512 + n];
    out[idx] = s;
}

// ---------------------------------------------------------------- launcher
extern "C" void kernel_launch(void* const* d_in, const int* in_sizes, int n_in,
                              void* d_out, int out_size, void* d_ws, size_t ws_size,
                              hipStream_t stream) {
    const float* x_inp    = (const float*)d_in[0];
    const float* conv_w   = (const float*)d_in[1];
    const float* cls_emb  = (const float*)d_in[2];
    const float* pos_emb  = (const float*)d_in[3];
    const float* ln_pre_w = (const float*)d_in[4];
    const float* ln_pre_b = (const float*)d_in[5];
    const float* ln1_w    = (const float*)d_in[6];
    const float* ln1_b    = (const float*)d_in[7];
    const float* qkv_w    = (const float*)d_in[8];
    const float* qkv_b    = (const float*)d_in[9];
    const float* out_w    = (const float*)d_in[10];
    const float* out_b    = (const float*)d_in[11];
    const float* ln2_w    = (const float*)d_in[12];
    const float* ln2_b    = (const float*)d_in[13];
    const float* fc1_w    = (const float*)d_in[14];
    const float* fc1_b    = (const float*)d_in[15];
    const float* fc2_w    = (const float*)d_in[16];
    const float* fc2_b    = (const float*)d_in[17];
    const float* ln_post_w= (const float*)d_in[18];
    const float* ln_post_b= (const float*)d_in[19];
    const float* proj     = (const float*)d_in[20];

    char* w = (char*)d_ws;
    __hip_bfloat16* wqkv = (__hip_bfloat16*)w; w += (size_t)LAYERS * 2304 * DMODEL * 2;
    __hip_bfloat16* wout = (__hip_bfloat16*)w; w += (size_t)LAYERS * DMODEL * DMODEL * 2;
    __hip_bfloat16* wfc1 = (__hip_bfloat16*)w; w += (size_t)LAYERS * FFDIM * DMODEL * 2;
    __hip_bfloat16* wfc2 = (__hip_bfloat16*)w; w += (size_t)LAYERS * DMODEL * FFDIM * 2;
    __hip_bfloat16* wconv= (__hip_bfloat16*)w; w += (size_t)DMODEL * DMODEL * 2;
    float* x             = (float*)w;          w += (size_t)MROWS * DMODEL * 4;
    __hip_bfloat16* y    = (__hip_bfloat16*)w; w += (size_t)MPAD * DMODEL * 2;
    __hip_bfloat16* qkvb = (__hip_bfloat16*)w; w += (size_t)MPAD * 2304 * 2;
    __hip_bfloat16* attno= (__hip_bfloat16*)w; w += (size_t)MPAD * DMODEL * 2;
    __hip_bfloat16* h1   = (__hip_bfloat16*)w; w += (size_t)MPAD * FFDIM * 2;
    __hip_bfloat16* patches = (__hip_bfloat16*)w; w += (size_t)NPATCH * BATCH * DMODEL * 2;
    float* clsb          = (float*)w;          w += (size_t)BATCH * DMODEL * 4;

    const long nqkv = (long)LAYERS * 2304 * DMODEL;
    const long nout = (long)LAYERS * DMODEL * DMODEL;
    const long nfc  = (long)LAYERS * FFDIM * DMODEL;
    const long ncv  = (long)DMODEL * DMODEL;
    int nblk = (int)((nqkv + nout + 2 * nfc + ncv) / 32768);
    cvt_merged_kernel<<<nblk, 256, 0, stream>>>(
        qkv_w, wqkv, nqkv, out_w, wout, nout,
        fc1_w, wfc1, nfc, fc2_w, wfc2, nfc, conv_w, wconv, ncv);

    im2col_kernel<<<NPATCH * BATCH, 256, 0, stream>>>(x_inp, patches);
    gemm64k<M_PATCH><<<98 * 6, 256, 0, stream>>>(
        patches, wconv, nullptr, x, nullptr, NPATCH * BATCH, DMODEL, DMODEL, 6, pos_emb);
    cls_token_kernel<<<BATCH, 256, 0, stream>>>(cls_emb, pos_emb, x);
    ln_kernel<0><<<MROWS / 4, 256, 0, stream>>>(x, x, ln_pre_w, ln_pre_b,
                                                DMODEL, DMODEL, MROWS);

    for (int l = 0; l < LAYERS; ++l) {
        ln_kernel<1><<<MROWS / 4, 256, 0, stream>>>(x, y, ln1_w + l * DMODEL,
                                                    ln1_b + l * DMODEL, DMODEL, DMODEL, MROWS);
        gemm128<M_QKVB><<<50 * 18, 256, 0, stream>>>(
            y, wqkv + (long)l * 2304 * DMODEL, qkv_b + (long)l * 2304, qkvb,
            MROWS, 2304, DMODEL, 18);
        attn_kernel<<<BATCH * NHEADS, 256, 0, stream>>>(qkvb, attno);
        gemm64k<M_ACC><<<99 * 6, 256, 0, stream>>>(
            attno, wout + (long)l * DMODEL * DMODEL, out_b + (long)l * DMODEL, x, nullptr,
            MROWS, DMODEL, DMODEL, 6, nullptr);
        ln_kernel<1><<<MROWS / 4, 256, 0, stream>>>(x, y, ln2_w + l * DMODEL,
                                                    ln2_b + l * DMODEL, DMODEL, DMODEL, MROWS);
        gemm128<M_GELU><<<50 * 24, 256, 0, stream>>>(
            y, wfc1 + (long)l * FFDIM * DMODEL, fc1_b + (long)l * FFDIM, h1,
            MROWS, FFDIM, DMODEL, 24);
        gemm64k<M_ACC><<<99 * 6, 256, 0, stream>>>(
            h1, wfc2 + (long)l * DMODEL * FFDIM, fc2_b + (long)l * DMODEL, x, nullptr,
            MROWS, DMODEL, FFDIM, 6, nullptr);
    }

    ln_kernel<0><<<8, 256, 0, stream>>>(x, clsb, ln_post_w, ln_post_b,
                                        (long)SEQ * DMODEL, DMODEL, BATCH);
    proj_kernel<<<(BATCH * OUTD) / 256, 256, 0, stream>>>(clsb, proj, (float*)d_out);
}

// Round 25
// 2761.160 us; speedup vs baseline: 1.0197x; 1.0030x over previous
//
#include <hip/hip_runtime.h>
#include <hip/hip_bf16.h>

// CLIP ViT-B/16 visual forward — Round 25: R24 (2769us best) with LayerNorm
// switched to single-pass moments (sum + sumsq reduced in ONE interleaved
// shuffle tree -> half the serial reduction latency). All else frozen.

#define LAYERS 12
#define DMODEL 768
#define NHEADS 12
#define DHEAD  64
#define FFDIM  3072
#define BATCH  32
#define SEQ    197
#define NPATCH 196
#define OUTD   512
#define MROWS  (BATCH * SEQ)   // 6304
#define MPAD   6400
#define SPAD   208
#define VSTR   208

typedef __attribute__((ext_vector_type(4))) float f32x4;
typedef __attribute__((ext_vector_type(8))) short bf16x8;

enum { M_F32 = 0, M_ACC = 1, M_GELU = 2, M_PATCH = 3, M_QKVB = 4 };

__device__ __forceinline__ float b2f(short s) {
    unsigned u = ((unsigned)(unsigned short)s) << 16;
    return __builtin_bit_cast(float, u);
}
__device__ __forceinline__ short f2b(float f) {
    __hip_bfloat16 h = __float2bfloat16(f);
    return __builtin_bit_cast(short, h);
}
__device__ __forceinline__ unsigned short f2bu(float f) {
    __hip_bfloat16 h = __float2bfloat16(f);
    return __builtin_bit_cast(unsigned short, h);
}
__device__ __forceinline__ unsigned pack2(float lo, float hi) {
    return (unsigned)f2bu(lo) | ((unsigned)f2bu(hi) << 16);
}

__device__ __forceinline__ void gl2lds16(const void* g, void* l) {
    __builtin_amdgcn_global_load_lds(
        (const __attribute__((address_space(1))) void*)g,
        (__attribute__((address_space(3))) void*)l, 16, 0, 0);
}

// ---------------------------------------------------------------- weight cvt
__global__ __launch_bounds__(256) void cvt_merged_kernel(
    const float* __restrict__ s0, __hip_bfloat16* __restrict__ d0, long n0,
    const float* __restrict__ s1, __hip_bfloat16* __restrict__ d1, long n1,
    const float* __restrict__ s2, __hip_bfloat16* __restrict__ d2, long n2,
    const float* __restrict__ s3, __hip_bfloat16* __restrict__ d3, long n3,
    const float* __restrict__ s4, __hip_bfloat16* __restrict__ d4, long n4)
{
    const long SPAN = 32768;
    long start = (long)blockIdx.x * SPAN;
    long e0 = n0, e1 = e0 + n1, e2 = e1 + n2, e3 = e2 + n3;
    const float* s; __hip_bfloat16* d; long base;
    if (start < e0)      { s = s0; d = d0; base = 0; }
    else if (start < e1) { s = s1; d = d1; base = e0; }
    else if (start < e2) { s = s2; d = d2; base = e1; }
    else if (start < e3) { s = s3; d = d3; base = e2; }
    else                 { s = s4; d = d4; base = e3; }
    long off = start - base;
    #pragma unroll 4
    for (long i = off + (long)threadIdx.x * 8; i < off + SPAN; i += 2048) {
        f32x4 v0 = __builtin_nontemporal_load(reinterpret_cast<const f32x4*>(&s[i]));
        f32x4 v1 = __builtin_nontemporal_load(reinterpret_cast<const f32x4*>(&s[i + 4]));
        int4 u;
        u.x = (int)pack2(v0[0], v0[1]);
        u.y = (int)pack2(v0[2], v0[3]);
        u.z = (int)pack2(v1[0], v1[1]);
        u.w = (int)pack2(v1[2], v1[3]);
        *reinterpret_cast<int4*>(&d[i]) = u;
    }
}

// ---------------------------------------------------------------- im2col
__global__ __launch_bounds__(256) void im2col_kernel(
    const float* __restrict__ x_inp, __hip_bfloat16* __restrict__ patches)
{
    int bp = blockIdx.x;
    int b = bp / NPATCH, p = bp % NPATCH;
    int py = p / 14, px = p % 14;
    const float* xb = x_inp + (long)b * 3 * 224 * 224;
    for (int e = threadIdx.x; e < 768; e += 256) {
        int c = e >> 8, i = (e >> 4) & 15, j = e & 15;
        patches[(long)bp * 768 + e] =
            __float2bfloat16(xb[((long)c * 224 + py * 16 + i) * 224 + px * 16 + j]);
    }
}

__global__ __launch_bounds__(256) void cls_token_kernel(
    const float* __restrict__ cls_emb, const float* __restrict__ pos_emb,
    float* __restrict__ x)
{
    int b = blockIdx.x;
    for (int d = threadIdx.x; d < DMODEL; d += 256)
        x[(long)b * SEQ * DMODEL + d] = cls_emb[d] + pos_emb[d];
}

// ---------------------------------------------------------------- layernorm
// one WAVE per row; 4 rows/block. SINGLE-PASS moments: sum & sumsq reduced
// in one interleaved shuffle tree (independent chains -> ILP).
template<int OB>
__global__ __launch_bounds__(256) void ln_kernel(
    const float* __restrict__ in, void* __restrict__ out,
    const float* __restrict__ w, const float* __restrict__ bb,
    long in_stride, long out_stride, int nrows)
{
    int row = blockIdx.x * 4 + (threadIdx.x >> 6);
    if (row >= nrows) return;
    int lane = threadIdx.x & 63;
    const float* xr = in + (long)row * in_stride;

    float4 v[3];
    float s = 0.f, q = 0.f;
    #pragma unroll
    for (int i = 0; i < 3; ++i) {
        v[i] = *reinterpret_cast<const float4*>(&xr[i * 256 + lane * 4]);
        s += v[i].x + v[i].y + v[i].z + v[i].w;
        q += v[i].x * v[i].x + v[i].y * v[i].y + v[i].z * v[i].z + v[i].w * v[i].w;
    }
    #pragma unroll
    for (int off = 32; off; off >>= 1) {
        s += __shfl_xor(s, off);
        q += __shfl_xor(q, off);
    }
    float mean = s * (1.0f / DMODEL);
    float var = fmaxf(q * (1.0f / DMODEL) - mean * mean, 0.f);
    float rstd = rsqrtf(var + 1e-5f);

    #pragma unroll
    for (int i = 0; i < 3; ++i) {
        int d0 = i * 256 + lane * 4;
        float4 wv = *reinterpret_cast<const float4*>(&w[d0]);
        float4 bv = *reinterpret_cast<const float4*>(&bb[d0]);
        float o0 = (v[i].x - mean) * rstd * wv.x + bv.x;
        float o1 = (v[i].y - mean) * rstd * wv.y + bv.y;
        float o2 = (v[i].z - mean) * rstd * wv.z + bv.z;
        float o3 = (v[i].w - mean) * rstd * wv.w + bv.w;
        if (OB) {
            ushort4 u;
            u.x = f2bu(o0); u.y = f2bu(o1); u.z = f2bu(o2); u.w = f2bu(o3);
            *reinterpret_cast<ushort4*>(
                &((__hip_bfloat16*)out)[(long)row * out_stride + d0]) = u;
        } else {
            float4 o = make_float4(o0, o1, o2, o3);
            *reinterpret_cast<float4*>(&((float*)out)[(long)row * out_stride + d0]) = o;
        }
    }
}

// ---------------------------------------------------------------- GEMM 64k
// 64x128 tile, BK=128, SINGLE-buffer 48KB LDS (3 blocks/CU). 4 waves, each
// 64x32 out. SWAPPED mfma operands: lane = C-row (fixed), regs = 4 cols.
template<int MODE>
__global__ __launch_bounds__(256) void gemm64k(
    const __hip_bfloat16* __restrict__ A, const __hip_bfloat16* __restrict__ W,
    const float* __restrict__ bias, float* __restrict__ Cf,
    __hip_bfloat16* __restrict__ Cb, int M, int N, int K, int NB,
    const float* __restrict__ pos)
{
    __shared__ short As[64 * 128];    // 16KB
    __shared__ short Bs[128 * 128];   // 32KB
    int tid = threadIdx.x, lane = tid & 63, wv = tid >> 6;

    int nwg = gridDim.x, bid = blockIdx.x;
    int qq = nwg >> 3, rr = nwg & 7;
    int xcd = bid & 7, idx = bid >> 3;
    int newid = (xcd < rr ? xcd * (qq + 1) : rr * (qq + 1) + (xcd - rr) * qq) + idx;

    int bm = (newid / NB) * 64, bn = (newid % NB) * 128;
    int wn = wv * 32;
    f32x4 acc[4][2] = {};

    int sr = tid >> 4, scn = tid & 15;
    int c_log = scn ^ sr;
    const short* Ag = (const short*)A + (long)(bm + sr) * K + (c_log << 3);
    const short* Bg = (const short*)W + (long)(bn + sr) * K + (c_log << 3);
    const long K16 = (long)16 * K;

    int lg = lane >> 4, lr16 = lane & 15;
    int aoff[4][4], boff[4][2];
    #pragma unroll
    for (int s = 0; s < 4; ++s) {
        int kc = (s << 2) | lg;
        #pragma unroll
        for (int i = 0; i < 4; ++i) {
            int ra = i * 16 + lr16;
            aoff[s][i] = (ra << 7) + (((kc ^ (ra & 15))) << 3);
        }
        #pragma unroll
        for (int j = 0; j < 2; ++j) {
            int rb = wn + j * 16 + lr16;
            boff[s][j] = (rb << 7) + (((kc ^ (rb & 15))) << 3);
        }
    }

    const int KT = K >> 7;
    for (int t = 0; t < KT; ++t) {
        if (t) __syncthreads();
        int kt = t << 7;
        #pragma unroll
        for (int p = 0; p < 4; ++p)
            gl2lds16(Ag + p * K16 + kt, (char*)As + p * 4096 + tid * 16);
        #pragma unroll
        for (int p = 0; p < 8; ++p)
            gl2lds16(Bg + p * K16 + kt, (char*)Bs + p * 4096 + tid * 16);
        __syncthreads();

        #pragma unroll
        for (int s = 0; s < 4; ++s) {
            bf16x8 af[4], bfr[2];
            #pragma unroll
            for (int i = 0; i < 4; ++i)
                af[i] = *reinterpret_cast<const bf16x8*>(&As[aoff[s][i]]);
            #pragma unroll
            for (int j = 0; j < 2; ++j)
                bfr[j] = *reinterpret_cast<const bf16x8*>(&Bs[boff[s][j]]);
            #pragma unroll
            for (int mi = 0; mi < 4; ++mi)
                #pragma unroll
                for (int ni = 0; ni < 2; ++ni)
                    acc[mi][ni] = __builtin_amdgcn_mfma_f32_16x16x32_bf16(
                        bfr[ni], af[mi], acc[mi][ni], 0, 0, 0);
        }
    }

    #pragma unroll
    for (int mi = 0; mi < 4; ++mi) {
        int row = bm + mi * 16 + lr16;
        if (row >= M) continue;
        #pragma unroll
        for (int ni = 0; ni < 2; ++ni) {
            int colb = bn + wn + ni * 16 + lg * 4;
            f32x4 a4 = acc[mi][ni];
            if (MODE == M_PATCH) {
                int pb = row / 196, pp = row - pb * 196;
                float* dst = &Cf[((long)(pb * SEQ + 1 + pp)) * DMODEL + colb];
                const float* pv = &pos[(long)(1 + pp) * DMODEL + colb];
                float4 pw = *reinterpret_cast<const float4*>(pv);
                float4 o = make_float4(a4[0] + pw.x, a4[1] + pw.y,
                                       a4[2] + pw.z, a4[3] + pw.w);
                *reinterpret_cast<float4*>(dst) = o;
            } else {
                float4 bw = *reinterpret_cast<const float4*>(&bias[colb]);
                float* dst = &Cf[(long)row * N + colb];
                if (MODE == M_ACC) {
                    float4 old = *reinterpret_cast<const float4*>(dst);
                    float4 o = make_float4(old.x + a4[0] + bw.x, old.y + a4[1] + bw.y,
                                           old.z + a4[2] + bw.z, old.w + a4[3] + bw.w);
                    *reinterpret_cast<float4*>(dst) = o;
                } else {
                    float4 o = make_float4(a4[0] + bw.x, a4[1] + bw.y,
                                           a4[2] + bw.z, a4[3] + bw.w);
                    *reinterpret_cast<float4*>(dst) = o;
                }
            }
        }
    }
}

// ---------------------------------------------------------------- GEMM 128sq
// 128x128 tile, BK=64, SINGLE-buffer 32KB LDS (5 blocks/CU), 4 waves (2x2).
// SWAPPED mfma operands -> packed 8B bf16 stores.
template<int MODE>
__global__ __launch_bounds__(256) void gemm128(
    const __hip_bfloat16* __restrict__ A, const __hip_bfloat16* __restrict__ W,
    const float* __restrict__ bias, __hip_bfloat16* __restrict__ Cb,
    int M, int N, int K, int NB)
{
    __shared__ short As[128 * 64];   // 16KB
    __shared__ short Bs[128 * 64];   // 16KB
    int tid = threadIdx.x, lane = tid & 63, wv = tid >> 6;

    int nwg = gridDim.x, bid = blockIdx.x;
    int qq = nwg >> 3, rr = nwg & 7;
    int xcd = bid & 7, idx = bid >> 3;
    int newid = (xcd < rr ? xcd * (qq + 1) : rr * (qq + 1) + (xcd - rr) * qq) + idx;

    int bm = (newid / NB) * 128, bn = (newid % NB) * 128;
    int wr = wv >> 1, wc = wv & 1;
    f32x4 acc[4][4] = {};

    int sr = tid >> 3, scn = tid & 7;
    int c_log = scn ^ (sr & 7);
    const short* Ag = (const short*)A + (long)(bm + sr) * K + (c_log << 3);
    const short* Bg = (const short*)W + (long)(bn + sr) * K + (c_log << 3);
    const long K32 = (long)32 * K;

    int lg = lane >> 4, lr16 = lane & 15;
    int aoff[2][4], boff[2][4];
    #pragma unroll
    for (int s = 0; s < 2; ++s) {
        int kc = (s << 2) | lg;
        #pragma unroll
        for (int i = 0; i < 4; ++i) {
            int ra = wr * 64 + i * 16 + lr16;
            aoff[s][i] = (ra << 6) + ((kc ^ (ra & 7)) << 3);
            int rb = wc * 64 + i * 16 + lr16;
            boff[s][i] = (rb << 6) + ((kc ^ (rb & 7)) << 3);
        }
    }

    const int KT = K >> 6;
    for (int t = 0; t < KT; ++t) {
        if (t) __syncthreads();
        int kt = t << 6;
        #pragma unroll
        for (int p = 0; p < 4; ++p) {
            gl2lds16(Ag + p * K32 + kt, (char*)As + p * 4096 + tid * 16);
            gl2lds16(Bg + p * K32 + kt, (char*)Bs + p * 4096 + tid * 16);
        }
        __syncthreads();

        #pragma unroll
        for (int s = 0; s < 2; ++s) {
            bf16x8 af[4], bfr[4];
            #pragma unroll
            for (int i = 0; i < 4; ++i)
                af[i] = *reinterpret_cast<const bf16x8*>(&As[aoff[s][i]]);
            #pragma unroll
            for (int j = 0; j < 4; ++j)
                bfr[j] = *reinterpret_cast<const bf16x8*>(&Bs[boff[s][j]]);
            #pragma unroll
            for (int mi = 0; mi < 4; ++mi)
                #pragma unroll
                for (int ni = 0; ni < 4; ++ni)
                    acc[mi][ni] = __builtin_amdgcn_mfma_f32_16x16x32_bf16(
                        bfr[ni], af[mi], acc[mi][ni], 0, 0, 0);
        }
    }

    #pragma unroll
    for (int mi = 0; mi < 4; ++mi) {
        int row = bm + wr * 64 + mi * 16 + lr16;
        if (row >= M) continue;
        #pragma unroll
        for (int ni = 0; ni < 4; ++ni) {
            int colb = bn + wc * 64 + ni * 16 + lg * 4;
            f32x4 a4 = acc[mi][ni];
            float4 bw = *reinterpret_cast<const float4*>(&bias[colb]);
            float v0 = a4[0] + bw.x, v1 = a4[1] + bw.y;
            float v2 = a4[2] + bw.z, v3 = a4[3] + bw.w;
            if (MODE == M_GELU) {
                v0 = v0 / (1.f + __expf(-1.702f * v0));
                v1 = v1 / (1.f + __expf(-1.702f * v1));
                v2 = v2 / (1.f + __expf(-1.702f * v2));
                v3 = v3 / (1.f + __expf(-1.702f * v3));
            }
            uint2 u;
            u.x = pack2(v0, v1);
            u.y = pack2(v2, v3);
            *reinterpret_cast<uint2*>(&Cb[(long)row * N + colb]) = u;
        }
    }
}

// ---------------------------------------------------------------- attention
// one block (256 thr, 4 waves) per (b,h); K,V staged in LDS. PV uses
// SWAPPED operands: lane holds q-row, regs = 4 consecutive d-cols -> 8B stores.
__global__ __launch_bounds__(256) void attn_kernel(
    const __hip_bfloat16* __restrict__ qkv, __hip_bfloat16* __restrict__ o)
{
    int bh = blockIdx.x;
    int b = bh / NHEADS, h = bh % NHEADS;
    int tid = threadIdx.x, lane = tid & 63, wv = tid >> 6;
    __shared__ short Ks[SPAD * 64];
    __shared__ short Vt[64 * VSTR];
    __shared__ short Ps[4][16 * VSTR];
    const short* base = (const short*)qkv + (long)b * SEQ * 2304;

    for (int idx = tid; idx < SPAD * 8; idx += 256) {
        int r = idx >> 3, c = idx & 7;
        int4 val = make_int4(0, 0, 0, 0);
        if (r < SEQ)
            val = *reinterpret_cast<const int4*>(base + (long)r * 2304 + 768 + h * 64 + c * 8);
        *reinterpret_cast<int4*>(&Ks[r * 64 + ((c ^ (r & 7)) << 3)]) = val;
    }
    for (int idx = tid; idx < SPAD * 64; idx += 256) {
        int k = idx >> 6, d = idx & 63;
        short v = (k < SEQ) ? base[(long)k * 2304 + 1536 + h * 64 + d] : (short)0;
        Vt[d * VSTR + k] = v;
    }
    __syncthreads();

    int lg = lane >> 4, lr = lane & 15;
    short* Pw = Ps[wv];

    for (int ch = wv; ch < 13; ch += 4) {
        int q0 = ch * 16;
        const short* qp = (const short*)qkv +
            ((long)(b * SEQ) + q0 + lr) * 2304 + h * 64 + (lg << 3);
        bf16x8 qa = *reinterpret_cast<const bf16x8*>(qp);
        bf16x8 qb = *reinterpret_cast<const bf16x8*>(qp + 32);

        f32x4 sc[13];
        #pragma unroll
        for (int f = 0; f < 13; ++f) sc[f] = (f32x4){0.f, 0.f, 0.f, 0.f};
        #pragma unroll
        for (int f = 0; f < 13; ++f) {
            int row = f * 16 + lr;
            int sw = row & 7;
            const short* kr = &Ks[row * 64];
            bf16x8 k0 = *reinterpret_cast<const bf16x8*>(&kr[((lg + 0) ^ sw) << 3]);
            bf16x8 k1 = *reinterpret_cast<const bf16x8*>(&kr[((lg + 4) ^ sw) << 3]);
            sc[f] = __builtin_amdgcn_mfma_f32_16x16x32_bf16(qa, k0, sc[f], 0, 0, 0);
            sc[f] = __builtin_amdgcn_mfma_f32_16x16x32_bf16(qb, k1, sc[f], 0, 0, 0);
        }

        float mrow[4] = {-1e30f, -1e30f, -1e30f, -1e30f};
        #pragma unroll
        for (int f = 0; f < 13; ++f) {
            bool ok = f * 16 + lr < SEQ;
            #pragma unroll
            for (int r = 0; r < 4; ++r)
                if (ok) mrow[r] = fmaxf(mrow[r], sc[f][r] * 0.125f);
        }
        #pragma unroll
        for (int r = 0; r < 4; ++r)
            #pragma unroll
            for (int off = 8; off; off >>= 1)
                mrow[r] = fmaxf(mrow[r], __shfl_xor(mrow[r], off));
        float esum[4] = {0.f, 0.f, 0.f, 0.f};
        #pragma unroll
        for (int f = 0; f < 13; ++f) {
            bool ok = f * 16 + lr < SEQ;
            #pragma unroll
            for (int r = 0; r < 4; ++r) {
                float e = ok ? __expf(sc[f][r] * 0.125f - mrow[r]) : 0.f;
                sc[f][r] = e;
                esum[r] += e;
            }
        }
        #pragma unroll
        for (int r = 0; r < 4; ++r)
            #pragma unroll
            for (int off = 8; off; off >>= 1)
                esum[r] += __shfl_xor(esum[r], off);
        float inv[4];
        #pragma unroll
        for (int r = 0; r < 4; ++r) inv[r] = 1.0f / esum[r];

        #pragma unroll
        for (int f = 0; f < 13; ++f)
            #pragma unroll
            for (int r = 0; r < 4; ++r)
                Pw[(lg * 4 + r) * VSTR + f * 16 + lr] = f2b(sc[f][r] * inv[r]);

        f32x4 oa[4] = {};
        #pragma unroll
        for (int ks = 0; ks < 7; ++ks) {
            int kb = ks * 32 + (lg << 3);
            bf16x8 pa = {};
            if (kb < SPAD) pa = *reinterpret_cast<const bf16x8*>(&Pw[lr * VSTR + kb]);
            #pragma unroll
            for (int d = 0; d < 4; ++d) {
                bf16x8 vb = {};
                if (kb < SPAD)
                    vb = *reinterpret_cast<const bf16x8*>(&Vt[(d * 16 + lr) * VSTR + kb]);
                oa[d] = __builtin_amdgcn_mfma_f32_16x16x32_bf16(vb, pa, oa[d], 0, 0, 0);
            }
        }

        int q = q0 + lr;
        if (q < SEQ) {
            __hip_bfloat16* orow = &o[((long)(b * SEQ + q)) * DMODEL + h * 64];
            #pragma unroll
            for (int d = 0; d < 4; ++d) {
                uint2 u;
                u.x = pack2(oa[d][0], oa[d][1]);
                u.y = pack2(oa[d][2], oa[d][3]);
                *reinterpret_cast<uint2*>(&orow[d * 16 + lg * 4]) = u;
            }
        }
    }
}

// ---------------------------------------------------------------- final proj
__global__ __launch_bounds__(256) void proj_kernel(
    const float* __restrict__ cls_ln, const float* __restrict__ proj,
    float* __restrict__ out)
{
    int idx = blockIdx.x * 256 + threadIdx.x;
    int m = idx >> 9, n = idx & 511;
    float s = 0.f;
    #pragma unroll 8
    for (int k = 0; k < 768; ++k)
        s += cls_ln[m * 768 + k] * proj[k * 512 + n];
    out[idx] = s;
}

// ---------------------------------------------------------------- launcher
extern "C" void kernel_launch(void* const* d_in, const int* in_sizes, int n_in,
                              void* d_out, int out_size, void* d_ws, size_t ws_size,
                              hipStream_t stream) {
    const float* x_inp    = (const float*)d_in[0];
    const float* conv_w   = (const float*)d_in[1];
    const float* cls_emb  = (const float*)d_in[2];
    const float* pos_emb  = (const float*)d_in[3];
    const float* ln_pre_w = (const float*)d_in[4];
    const float* ln_pre_b = (const float*)d_in[5];
    const float* ln1_w    = (const float*)d_in[6];
    const float* ln1_b    = (const float*)d_in[7];
    const float* qkv_w    = (const float*)d_in[8];
    const float* qkv_b    = (const float*)d_in[9];
    const float* out_w    = (const float*)d_in[10];
    const float* out_b    = (const float*)d_in[11];
    const float* ln2_w    = (const float*)d_in[12];
    const float* ln2_b    = (const float*)d_in[13];
    const float* fc1_w    = (const float*)d_in[14];
    const float* fc1_b    = (const float*)d_in[15];
    const float* fc2_w    = (const float*)d_in[16];
    const float* fc2_b    = (const float*)d_in[17];
    const float* ln_post_w= (const float*)d_in[18];
    const float* ln_post_b= (const float*)d_in[19];
    const float* proj     = (const float*)d_in[20];

    char* w = (char*)d_ws;
    __hip_bfloat16* wqkv = (__hip_bfloat16*)w; w += (size_t)LAYERS * 2304 * DMODEL * 2;
    __hip_bfloat16* wout = (__hip_bfloat16*)w; w += (size_t)LAYERS * DMODEL * DMODEL * 2;
    __hip_bfloat16* wfc1 = (__hip_bfloat16*)w; w += (size_t)LAYERS * FFDIM * DMODEL * 2;
    __hip_bfloat16* wfc2 = (__hip_bfloat16*)w; w += (size_t)LAYERS * DMODEL * FFDIM * 2;
    __hip_bfloat16* wconv= (__hip_bfloat16*)w; w += (size_t)DMODEL * DMODEL * 2;
    float* x             = (float*)w;          w += (size_t)MROWS * DMODEL * 4;
    __hip_bfloat16* y    = (__hip_bfloat16*)w; w += (size_t)MPAD * DMODEL * 2;
    __hip_bfloat16* qkvb = (__hip_bfloat16*)w; w += (size_t)MPAD * 2304 * 2;
    __hip_bfloat16* attno= (__hip_bfloat16*)w; w += (size_t)MPAD * DMODEL * 2;
    __hip_bfloat16* h1   = (__hip_bfloat16*)w; w += (size_t)MPAD * FFDIM * 2;
    __hip_bfloat16* patches = (__hip_bfloat16*)w; w += (size_t)NPATCH * BATCH * DMODEL * 2;
    float* clsb          = (float*)w;          w += (size_t)BATCH * DMODEL * 4;

    const long nqkv = (long)LAYERS * 2304 * DMODEL;
    const long nout = (long)LAYERS * DMODEL * DMODEL;
    const long nfc  = (long)LAYERS * FFDIM * DMODEL;
    const long ncv  = (long)DMODEL * DMODEL;
    int nblk = (int)((nqkv + nout + 2 * nfc + ncv) / 32768);
    cvt_merged_kernel<<<nblk, 256, 0, stream>>>(
        qkv_w, wqkv, nqkv, out_w, wout, nout,
        fc1_w, wfc1, nfc, fc2_w, wfc2, nfc, conv_w, wconv, ncv);

    im2col_kernel<<<NPATCH * BATCH, 256, 0, stream>>>(x_inp, patches);
    gemm64k<M_PATCH><<<98 * 6, 256, 0, stream>>>(
        patches, wconv, nullptr, x, nullptr, NPATCH * BATCH, DMODEL, DMODEL, 6, pos_emb);
    cls_token_kernel<<<BATCH, 256, 0, stream>>>(cls_emb, pos_emb, x);
    ln_kernel<0><<<MROWS / 4, 256, 0, stream>>>(x, x, ln_pre_w, ln_pre_b,
                                                DMODEL, DMODEL, MROWS);

    for (int l = 0; l < LAYERS; ++l) {
        ln_kernel<1><<<MROWS / 4, 256, 0, stream>>>(x, y, ln1_w + l * DMODEL,
                                                    ln1_b + l * DMODEL, DMODEL, DMODEL, MROWS);
        gemm128<M_QKVB><<<50 * 18, 256, 0, stream>>>(
            y, wqkv + (long)l * 2304 * DMODEL, qkv_b + (long)l * 2304, qkvb,
            MROWS, 2304, DMODEL, 18);
        attn_kernel<<<BATCH * NHEADS, 256, 0, stream>>>(qkvb, attno);
        gemm64k<M_ACC><<<99 * 6, 256, 0, stream>>>(
            attno, wout + (long)l * DMODEL * DMODEL, out_b + (long)l * DMODEL, x, nullptr,
            MROWS, DMODEL, DMODEL, 6, nullptr);
        ln_kernel<1><<<MROWS / 4, 256, 0, stream>>>(x, y, ln2_w + l * DMODEL,
                                                    ln2_b + l * DMODEL, DMODEL, DMODEL, MROWS);
        gemm128<M_GELU><<<50 * 24, 256, 0, stream>>>(
            y, wfc1 + (long)l * FFDIM * DMODEL, fc1_b + (long)l * FFDIM, h1,
            MROWS, FFDIM, DMODEL, 24);
        gemm64k<M_ACC><<<99 * 6, 256, 0, stream>>>(
            h1, wfc2 + (long)l * DMODEL * FFDIM, fc2_b + (long)l * DMODEL, x, nullptr,
            MROWS, DMODEL, FFDIM, 6, nullptr);
    }

    ln_kernel<0><<<8, 256, 0, stream>>>(x, clsb, ln_post_w, ln_post_b,
                                        (long)SEQ * DMODEL, DMODEL, BATCH);
    proj_kernel<<<(BATCH * OUTD) / 256, 256, 0, stream>>>(clsb, proj, (float*)d_out);
}